// Round 4
// baseline (892.019 us; speedup 1.0000x reference)
//
#include <hip/hip_runtime.h>

typedef unsigned short u16;
typedef unsigned int   u32;
typedef float f32x4  __attribute__((ext_vector_type(4)));

#define B_  32
#define T_  256
#define D_  512
#define V_  32000
#define M_  (B_*T_)     // 8192 tokens

// ------- gather: H0[m][d] = embed[seq[m]][d] (f32) -------
__global__ __launch_bounds__(256) void k_gather(const int* __restrict__ seq,
    const float* __restrict__ embed, float* __restrict__ H0){
  int t = threadIdx.x;
  int row = blockIdx.x*2 + (t>>7);
  int d = (t&127)*4;
  int tok = seq[row];
  f32x4 v = *(const f32x4*)(embed + (size_t)tok*D_ + d);
  *(f32x4*)(H0 + (size_t)row*D_ + d) = v;
}

// ------- plain f32 tiled GEMM: C[m][n] = sum_k A[m][k]*Bw[k][n] (+bias, EPI) -------
// EPI==1: relu(v+bias) -> C (N=1024)
// EPI==2: v+bias+res   -> C (res may alias C; per-element read-then-write by same thread)
template<int KTOT, int EPI>
__global__ __launch_bounds__(256) void k_gemm_f32(const float* __restrict__ A,
    const float* __restrict__ Bw, const float* __restrict__ bias,
    const float* res, float* C, int N, int NTILES){
  __shared__ float As[64][17];
  __shared__ float Bs[16][64];
  int mt = blockIdx.x / NTILES, nt = blockIdx.x % NTILES;
  int m0 = mt*64, n0 = nt*64;
  int t = threadIdx.x;
  int tx = t & 15, ty = t >> 4;          // 16x16 thread grid, 4x4 outputs each
  float acc[4][4] = {};
  for (int k0 = 0; k0 < KTOT; k0 += 16){
    #pragma unroll
    for (int e = 0; e < 4; ++e){
      int idx = t + e*256;               // 0..1023 = 64x16
      int r = idx >> 4, c = idx & 15;
      As[r][c] = A[(size_t)(m0+r)*KTOT + k0 + c];
    }
    #pragma unroll
    for (int e = 0; e < 4; ++e){
      int idx = t + e*256;               // 0..1023 = 16x64
      int r = idx >> 6, c = idx & 63;
      Bs[r][c] = Bw[(size_t)(k0+r)*N + n0 + c];
    }
    __syncthreads();
    #pragma unroll
    for (int k = 0; k < 16; ++k){
      float av[4], bv[4];
      #pragma unroll
      for (int i=0;i<4;++i) av[i] = As[ty*4+i][k];
      #pragma unroll
      for (int j=0;j<4;++j) bv[j] = Bs[k][tx*4+j];
      #pragma unroll
      for (int i=0;i<4;++i)
        #pragma unroll
        for (int j=0;j<4;++j) acc[i][j] += av[i]*bv[j];
    }
    __syncthreads();
  }
  #pragma unroll
  for (int i=0;i<4;++i){
    int row = m0 + ty*4 + i;
    #pragma unroll
    for (int j=0;j<4;++j){
      int col = n0 + tx*4 + j;
      float v = acc[i][j] + bias[col];
      if constexpr (EPI==1){
        v = fmaxf(v, 0.f);
      } else {
        v += res[(size_t)row*N + col];
      }
      C[(size_t)row*N + col] = v;
    }
  }
}

// ------- LayerNorm + per-token scalars (gate logit, demote score), all f32 -------
__global__ __launch_bounds__(256) void k_ln(const float* __restrict__ X,
    const float* __restrict__ g, const float* __restrict__ bb,
    const float* __restrict__ wgw, const float* __restrict__ wgb,
    const float* __restrict__ demw, const float* __restrict__ demb,
    float* __restrict__ H, float* __restrict__ wsl, float* __restrict__ dd){
  int m = blockIdx.x*4 + (threadIdx.x >> 6);
  int lane = threadIdx.x & 63;
  const float* x = X + (size_t)m*D_;
  float v[8];
  {
    f32x4 a  = *(const f32x4*)(x + lane*8);
    f32x4 b2 = *(const f32x4*)(x + lane*8 + 4);
    v[0]=a[0]; v[1]=a[1]; v[2]=a[2]; v[3]=a[3];
    v[4]=b2[0]; v[5]=b2[1]; v[6]=b2[2]; v[7]=b2[3];
  }
  float s = 0.f;
  #pragma unroll
  for (int i=0;i<8;++i) s += v[i];
  #pragma unroll
  for (int off=32;off;off>>=1) s += __shfl_xor(s, off);
  float mu = s * (1.f/512.f);
  float sq = 0.f;
  #pragma unroll
  for (int i=0;i<8;++i){ float d0 = v[i]-mu; sq += d0*d0; }
  #pragma unroll
  for (int off=32;off;off>>=1) sq += __shfl_xor(sq, off);
  float rstd = 1.f / sqrtf(sq*(1.f/512.f) + 1e-5f);
  float hw = 0.f, hd = 0.f;
  float hv[8];
  #pragma unroll
  for (int i=0;i<8;++i){
    int ci = lane*8+i;
    float h = (v[i]-mu)*rstd*g[ci] + bb[ci];
    hv[i] = h;
    hw += h*wgw[ci];
    hd += h*demw[ci];
  }
  float* Hr = H + (size_t)m*D_;
  f32x4 o0, o1;
  o0[0]=hv[0]; o0[1]=hv[1]; o0[2]=hv[2]; o0[3]=hv[3];
  o1[0]=hv[4]; o1[1]=hv[5]; o1[2]=hv[6]; o1[3]=hv[7];
  *(f32x4*)(Hr + lane*8)     = o0;
  *(f32x4*)(Hr + lane*8 + 4) = o1;
  #pragma unroll
  for (int off=32;off;off>>=1){ hw += __shfl_xor(hw,off); hd += __shfl_xor(hd,off); }
  if (lane==0){ wsl[m] = hw + wgb[0]; dd[m] = hd + demb[0]; }
}

// ------- sequential tiered-memory scan: indices-only automaton (1 wave / batch) -------
__global__ __launch_bounds__(64) void k_scan(const float* __restrict__ wsl,
                                             const float* __restrict__ dd,
                                             int* __restrict__ mem_tok){
  int b = blockIdx.x, lane = threadIdx.x;
  __shared__ float sdd[256];
  __shared__ int   swf[256];
  __shared__ int   stok[96];
  __shared__ int   ssa[96];
  for (int i=lane;i<256;i+=64){
    sdd[i] = dd[b*256+i];
    float xw = wsl[b*256+i];
    float sg = 1.f/(1.f + expf(-xw));
    swf[i] = (sg >= 0.4f) ? 1 : 0;
  }
  for (int i=lane;i<96;i+=64){ stok[i] = -1; ssa[i] = 0; }
  __syncthreads();
  int fm_tok = 0; int fu = 0;           // fast slot = lane (lane<32)
  for (int t=0;t<253;++t){
    if (stok[lane] >= 0) ssa[lane]++;
    if (lane < 32 && stok[64+lane] >= 0) ssa[64+lane]++;
    __syncthreads();
    if (swf[t]){
      unsigned long long bal = __ballot(lane < 32 && !fu);
      u32 fm32 = (u32)bal;
      int target;
      if (fm32){
        target = __builtin_ctz(fm32);           // first free fast slot
      } else {
        // argmin over demote scores of resident fast tokens (first-index ties)
        float vv = (lane < 32) ? sdd[fm_tok] : 3.0e38f;
        int idx = lane;
        #pragma unroll
        for (int off=32;off;off>>=1){
          float v2 = __shfl_xor(vv, off);
          int   i2 = __shfl_xor(idx, off);
          if (v2 < vv || (v2 == vv && i2 < idx)){ vv = v2; idx = i2; }
        }
        int dem = idx;
        int dh  = __shfl(fm_tok, dem);
        // slow slot: first free else first-index argmax age
        int cand = 0x7fffffff;
        if (stok[lane] < 0) cand = lane;
        if (lane < 32 && stok[64+lane] < 0) cand = min(cand, 64+lane);
        #pragma unroll
        for (int off=32;off;off>>=1) cand = min(cand, __shfl_xor(cand, off));
        int ss;
        if (cand != 0x7fffffff){ ss = cand; }
        else {
          int av = ssa[lane], ai = lane;
          if (lane < 32){ int a2 = ssa[64+lane]; if (a2 > av){ av = a2; ai = 64+lane; } }
          #pragma unroll
          for (int off=32;off;off>>=1){
            int v2 = __shfl_xor(av, off); int i2 = __shfl_xor(ai, off);
            if (v2 > av || (v2 == av && i2 < ai)){ av = v2; ai = i2; }
          }
          ss = ai;
        }
        if (lane == 0){ stok[ss] = dh; ssa[ss] = 0; }
        target = dem;
      }
      if (lane == target){ fm_tok = t; fu = 1; }
    }
    __syncthreads();
  }
  if (lane < 32) mem_tok[b*128 + lane] = fu ? fm_tok : -1;
  mem_tok[b*128 + 32 + lane] = stok[lane];
  if (lane < 32) mem_tok[b*128 + 96 + lane] = stok[64+lane];
}

// ------- read head: q, scores, softmax, ctx (transposed store), all f32 -------
__global__ __launch_bounds__(256) void k_readhead(const float* __restrict__ H,
    const int* __restrict__ mem_tok, const float* __restrict__ qw,
    const float* __restrict__ qb, float* __restrict__ ctxT){
  int b = blockIdx.x, tid = threadIdx.x;
  __shared__ float hl[512];
  __shared__ float qv[512];
  __shared__ float sc[128];
  __shared__ float at[128];
  __shared__ int   stk[128];
  __shared__ float red[2];
  const float* last = H + ((size_t)b*T_ + (T_-1))*D_;
  for (int i=tid;i<512;i+=256) hl[i] = last[i];
  __syncthreads();
  #pragma unroll
  for (int jj=0;jj<2;++jj){
    int j = tid + jj*256;
    float acc = qb[j];
    for (int i=0;i<512;++i) acc += hl[i]*qw[(size_t)i*512 + j];
    qv[j] = acc;
  }
  __syncthreads();
  if (tid < 128){
    int tok = mem_tok[b*128 + tid];
    stk[tid] = tok;
    float sv = -1e9f;
    if (tok >= 0){
      const float* hr = H + ((size_t)b*T_ + tok)*D_;
      float a0=0,a1=0,a2=0,a3=0;
      for (int i=0;i<512;i+=4){
        a0 += hr[i]*qv[i]; a1 += hr[i+1]*qv[i+1];
        a2 += hr[i+2]*qv[i+2]; a3 += hr[i+3]*qv[i+3];
      }
      sv = (a0+a1)+(a2+a3);
    }
    sc[tid] = sv;
  }
  __syncthreads();
  if (tid < 64){
    float m = fmaxf(sc[tid], sc[tid+64]);
    #pragma unroll
    for (int off=32;off;off>>=1) m = fmaxf(m, __shfl_xor(m, off));
    if (tid == 0) red[0] = m;
  }
  __syncthreads();
  if (tid < 128) at[tid] = expf(sc[tid] - red[0]);
  __syncthreads();
  if (tid < 64){
    float s2 = at[tid] + at[tid+64];
    #pragma unroll
    for (int off=32;off;off>>=1) s2 += __shfl_xor(s2, off);
    if (tid == 0) red[1] = s2;
  }
  __syncthreads();
  if (tid < 128) at[tid] = at[tid] / red[1];
  __syncthreads();
  #pragma unroll
  for (int jj=0;jj<2;++jj){
    int d0 = tid + jj*256;
    float acc = 0.f;
    for (int n=0;n<128;++n){
      int tok = stk[n];
      if (tok < 0) continue;
      acc += at[n] * H[((size_t)b*T_ + tok)*D_ + d0];
    }
    ctxT[(size_t)d0*32 + b] = acc;   // [D][B] for uniform (scalar) loads downstream
  }
}

// ------- out projection: out[b][c] = sum_k ctxT[k][b]*out_w[k][c] + out_b[c]; f32 store -------
__global__ __launch_bounds__(256) void k_outproj(const float* __restrict__ ctxT,
    const float* __restrict__ outw, const float* __restrict__ outb, float* __restrict__ out){
  int c = blockIdx.x*256 + threadIdx.x;
  float acc[32];
  #pragma unroll
  for (int i=0;i<32;++i) acc[i] = 0.f;
  for (int k=0;k<512;++k){
    float wv = outw[(size_t)k*V_ + c];
    const float* ct = ctxT + k*32;     // uniform address -> scalar loads
    #pragma unroll
    for (int i=0;i<32;++i) acc[i] += ct[i]*wv;
  }
  float bo = outb[c];
  #pragma unroll
  for (int i=0;i<32;++i) out[(size_t)i*V_ + c] = acc[i] + bo;
}

extern "C" void kernel_launch(void* const* d_in, const int* in_sizes, int n_in,
                              void* d_out, int out_size, void* d_ws, size_t ws_size,
                              hipStream_t stream) {
  const int*   seq   = (const int*)  d_in[0];
  const float* embed = (const float*)d_in[1];
  const float* ff1w  = (const float*)d_in[2];
  const float* ff1b  = (const float*)d_in[3];
  const float* ff2w  = (const float*)d_in[4];
  const float* ff2b  = (const float*)d_in[5];
  const float* lng   = (const float*)d_in[6];
  const float* lnb   = (const float*)d_in[7];
  const float* wgw   = (const float*)d_in[8];
  const float* wgb   = (const float*)d_in[9];
  const float* demw  = (const float*)d_in[10];
  const float* demb  = (const float*)d_in[11];
  const float* qw    = (const float*)d_in[12];
  const float* qb    = (const float*)d_in[13];
  const float* outw  = (const float*)d_in[14];
  const float* outb  = (const float*)d_in[15];
  float* out = (float*)d_out;
  char* ws = (char*)d_ws;

  // workspace layout (bytes) — total ~50.4 MB
  float* H0     = (float*)(ws + 0);                      // 8192*512*4   = 16,777,216 (residual -> X in place)
  float* HID    = (float*)(ws + 16777216);               // 8192*1024*4  = 33,554,432 (hidden -> H after LN)
  float* Hbuf   = (float*)(ws + 16777216);               // aliases HID (dead after GEMM2)
  float* wsl    = (float*)(ws + 50331648);               // 8192*4
  float* dd     = (float*)(ws + 50364416);               // 8192*4
  int*   memtok = (int*)  (ws + 50397184);               // 32*128*4
  float* ctxT   = (float*)(ws + 50413568);               // 512*32*4

  k_gather<<<M_/2, 256, 0, stream>>>(seq, embed, H0);
  // HID = relu(H0 @ ff1_w + ff1_b)                  [8192 x 1024]
  k_gemm_f32<512, 1><<<128*16, 256, 0, stream>>>(H0, ff1w, ff1b, (const float*)nullptr, HID, 1024, 16);
  // H0 = HID @ ff2_w + ff2_b + H0   (in place)      [8192 x 512]
  k_gemm_f32<1024,2><<<128*8, 256, 0, stream>>>(HID, ff2w, ff2b, H0, H0, 512, 8);
  // Hbuf = LN(H0)  (HID region is dead now)
  k_ln      <<<M_/4, 256, 0, stream>>>(H0, lng, lnb, wgw, wgb, demw, demb, Hbuf, wsl, dd);
  k_scan    <<<B_, 64, 0, stream>>>(wsl, dd, memtok);
  k_readhead<<<B_, 256, 0, stream>>>(Hbuf, memtok, qw, qb, ctxT);
  k_outproj <<<V_/256, 256, 0, stream>>>(ctxT, outw, outb, out);
}

// Round 5
// 810.585 us; speedup vs baseline: 1.1005x; 1.1005x over previous
//
#include <hip/hip_runtime.h>

typedef unsigned short u16;
typedef unsigned int   u32;
typedef unsigned long long u64;
typedef float f32x4  __attribute__((ext_vector_type(4)));

#define B_  32
#define T_  256
#define D_  512
#define V_  32000
#define M_  (B_*T_)     // 8192 tokens

// ------- gather: H0[m][d] = embed[seq[m]][d] (f32) -------
__global__ __launch_bounds__(256) void k_gather(const int* __restrict__ seq,
    const float* __restrict__ embed, float* __restrict__ H0){
  int t = threadIdx.x;
  int row = blockIdx.x*2 + (t>>7);
  int d = (t&127)*4;
  int tok = seq[row];
  f32x4 v = *(const f32x4*)(embed + (size_t)tok*D_ + d);
  *(f32x4*)(H0 + (size_t)row*D_ + d) = v;
}

// ------- f32 tiled GEMM, vectorized LDS: C[m][n] = sum_k A[m][k]*Bw[k][n] (+bias, EPI) -------
// EPI==1: relu(v+bias) -> C
// EPI==2: v+bias+res   -> C (res may alias C; per-element read-then-write by same thread)
template<int KTOT, int EPI>
__global__ __launch_bounds__(256) void k_gemm_f32(const float* __restrict__ A,
    const float* __restrict__ Bw, const float* __restrict__ bias,
    const float* res, float* C, int N, int NTILES){
  __shared__ float As2[16][68];   // k-major, +4 pad
  __shared__ float Bs[16][64];
  int mt = blockIdx.x / NTILES, nt = blockIdx.x % NTILES;
  int m0 = mt*64, n0 = nt*64;
  int t = threadIdx.x;
  int tx = t & 15, ty = t >> 4;          // 16x16 thread grid, 4x4 outputs each
  int ar = t >> 2, ac = (t & 3) * 4;     // A-tile load: 64 rows x 16 cols, f32x4 per thread
  int br = t >> 4, bc = (t & 15) * 4;    // B-tile load: 16 rows x 64 cols, f32x4 per thread
  float acc[4][4] = {};
  for (int k0 = 0; k0 < KTOT; k0 += 16){
    f32x4 aval = *(const f32x4*)(A  + (size_t)(m0+ar)*KTOT + k0 + ac);
    f32x4 bval = *(const f32x4*)(Bw + (size_t)(k0+br)*N   + n0 + bc);
    __syncthreads();                     // prior iteration's LDS reads done
    #pragma unroll
    for (int j=0;j<4;++j) As2[ac+j][ar] = aval[j];
    *(f32x4*)&Bs[br][bc] = bval;
    __syncthreads();
    #pragma unroll
    for (int k = 0; k < 16; ++k){
      f32x4 av = *(const f32x4*)&As2[k][ty*4];
      f32x4 bv = *(const f32x4*)&Bs[k][tx*4];
      #pragma unroll
      for (int i=0;i<4;++i)
        #pragma unroll
        for (int j=0;j<4;++j) acc[i][j] += av[i]*bv[j];
    }
  }
  #pragma unroll
  for (int i=0;i<4;++i){
    int row = m0 + ty*4 + i;
    #pragma unroll
    for (int j=0;j<4;++j){
      int col = n0 + tx*4 + j;
      float v = acc[i][j] + bias[col];
      if constexpr (EPI==1){
        v = fmaxf(v, 0.f);
      } else {
        v += res[(size_t)row*N + col];
      }
      C[(size_t)row*N + col] = v;
    }
  }
}

// ------- LayerNorm + per-token scalars (gate logit, demote score), all f32 -------
__global__ __launch_bounds__(256) void k_ln(const float* __restrict__ X,
    const float* __restrict__ g, const float* __restrict__ bb,
    const float* __restrict__ wgw, const float* __restrict__ wgb,
    const float* __restrict__ demw, const float* __restrict__ demb,
    float* __restrict__ H, float* __restrict__ wsl, float* __restrict__ dd){
  int m = blockIdx.x*4 + (threadIdx.x >> 6);
  int lane = threadIdx.x & 63;
  const float* x = X + (size_t)m*D_;
  float v[8];
  {
    f32x4 a  = *(const f32x4*)(x + lane*8);
    f32x4 b2 = *(const f32x4*)(x + lane*8 + 4);
    v[0]=a[0]; v[1]=a[1]; v[2]=a[2]; v[3]=a[3];
    v[4]=b2[0]; v[5]=b2[1]; v[6]=b2[2]; v[7]=b2[3];
  }
  float s = 0.f;
  #pragma unroll
  for (int i=0;i<8;++i) s += v[i];
  #pragma unroll
  for (int off=32;off;off>>=1) s += __shfl_xor(s, off);
  float mu = s * (1.f/512.f);
  float sq = 0.f;
  #pragma unroll
  for (int i=0;i<8;++i){ float d0 = v[i]-mu; sq += d0*d0; }
  #pragma unroll
  for (int off=32;off;off>>=1) sq += __shfl_xor(sq, off);
  float rstd = 1.f / sqrtf(sq*(1.f/512.f) + 1e-5f);
  float hw = 0.f, hd = 0.f;
  float hv[8];
  #pragma unroll
  for (int i=0;i<8;++i){
    int ci = lane*8+i;
    float h = (v[i]-mu)*rstd*g[ci] + bb[ci];
    hv[i] = h;
    hw += h*wgw[ci];
    hd += h*demw[ci];
  }
  float* Hr = H + (size_t)m*D_;
  f32x4 o0, o1;
  o0[0]=hv[0]; o0[1]=hv[1]; o0[2]=hv[2]; o0[3]=hv[3];
  o1[0]=hv[4]; o1[1]=hv[5]; o1[2]=hv[6]; o1[3]=hv[7];
  *(f32x4*)(Hr + lane*8)     = o0;
  *(f32x4*)(Hr + lane*8 + 4) = o1;
  #pragma unroll
  for (int off=32;off;off>>=1){ hw += __shfl_xor(hw,off); hd += __shfl_xor(hd,off); }
  if (lane==0){ wsl[m] = hw + wgb[0]; dd[m] = hd + demb[0]; }
}

// ------- sequential tiered-memory scan: register-only automaton (1 wave / batch) -------
// Fast slot i  <-> lane i (i<32): fm_tok, fu, fdd (demote score of held token).
// Slow slot s  <-> lane s (s<64): r0_*;  slot 64+s <-> lane s (s<32): r1_*.
// Write-gate flags precomputed as 4x u64 ballot masks; dd[t] broadcast via shfl.
__global__ __launch_bounds__(64) void k_scan(const float* __restrict__ wsl,
                                             const float* __restrict__ dd,
                                             int* __restrict__ mem_tok){
  int b = blockIdx.x, lane = threadIdx.x;
  const float* wb = wsl + b*256;
  const float* db = dd  + b*256;
  float d0 = db[lane], d1 = db[64+lane], d2 = db[128+lane], d3 = db[192+lane];
  float w0 = wb[lane], w1 = wb[64+lane], w2 = wb[128+lane], w3 = wb[192+lane];
  u64 m0 = __ballot(1.f/(1.f+expf(-w0)) >= 0.4f);
  u64 m1 = __ballot(1.f/(1.f+expf(-w1)) >= 0.4f);
  u64 m2 = __ballot(1.f/(1.f+expf(-w2)) >= 0.4f);
  u64 m3 = __ballot(1.f/(1.f+expf(-w3)) >= 0.4f);
  int  fm_tok = 0; bool fu = false; float fdd = 0.f;
  int  r0_tok = -1, r1_tok = -1;
  int  r0_age = 0,  r1_age = 0;
  for (int t = 0; t < 253; ++t){
    // age increments (pre-write, matching reference)
    if (r0_tok >= 0) r0_age++;
    if (lane < 32 && r1_tok >= 0) r1_age++;
    u64 m = (t<64)?m0:(t<128)?m1:(t<192)?m2:m3;
    if ((m >> (t & 63)) & 1ull){
      float dsel = (t<64)?d0:(t<128)?d1:(t<192)?d2:d3;
      float ddt = __shfl(dsel, t & 63);          // dd[b*256+t], all lanes
      u64 freeF = __ballot(lane < 32 && !fu);
      if (freeF){
        int target = __builtin_ctzll(freeF);     // first free fast slot
        if (lane == target){ fm_tok = t; fu = true; fdd = ddt; }
      } else {
        // argmin over resident fast demote scores (first-index ties)
        float vv = (lane < 32) ? fdd : 3.0e38f;
        int idx = lane;
        #pragma unroll
        for (int off=32;off;off>>=1){
          float v2 = __shfl_xor(vv, off);
          int   i2 = __shfl_xor(idx, off);
          if (v2 < vv || (v2 == vv && i2 < idx)){ vv = v2; idx = i2; }
        }
        int dem = idx;                           // uniform across lanes
        int dh_tok = __shfl(fm_tok, dem);        // demoted token (pre-overwrite)
        // slow slot: first free else first-index argmax age
        u64 f0 = __ballot(r0_tok < 0);
        u64 f1 = __ballot(lane < 32 && r1_tok < 0);
        int ss;
        if (f0)      ss = __builtin_ctzll(f0);
        else if (f1) ss = 64 + __builtin_ctzll(f1);
        else {
          int av = r0_age, ai = lane;
          if (lane < 32 && r1_age > av){ av = r1_age; ai = 64 + lane; }
          #pragma unroll
          for (int off=32;off;off>>=1){
            int v2 = __shfl_xor(av, off);
            int i2 = __shfl_xor(ai, off);
            if (v2 > av || (v2 == av && i2 < ai)){ av = v2; ai = i2; }
          }
          ss = ai;
        }
        if (ss < 64){ if (lane == ss)     { r0_tok = dh_tok; r0_age = 0; } }
        else        { if (lane == ss - 64){ r1_tok = dh_tok; r1_age = 0; } }
        if (lane == dem){ fm_tok = t; fdd = ddt; }   // fu stays true
      }
    }
  }
  if (lane < 32) mem_tok[b*128 + lane] = fu ? fm_tok : -1;
  mem_tok[b*128 + 32 + lane] = r0_tok;
  if (lane < 32) mem_tok[b*128 + 96 + lane] = r1_tok;
}

// ------- read head: q, scores, softmax, ctx (transposed store), all f32 -------
__global__ __launch_bounds__(256) void k_readhead(const float* __restrict__ H,
    const int* __restrict__ mem_tok, const float* __restrict__ qw,
    const float* __restrict__ qb, float* __restrict__ ctxT){
  int b = blockIdx.x, tid = threadIdx.x;
  __shared__ float hl[512];
  __shared__ float qv[512];
  __shared__ float sc[128];
  __shared__ float at[128];
  __shared__ int   stk[128];
  __shared__ float red[2];
  const float* last = H + ((size_t)b*T_ + (T_-1))*D_;
  for (int i=tid;i<512;i+=256) hl[i] = last[i];
  __syncthreads();
  #pragma unroll
  for (int jj=0;jj<2;++jj){
    int j = tid + jj*256;
    float acc = qb[j];
    for (int i=0;i<512;++i) acc += hl[i]*qw[(size_t)i*512 + j];
    qv[j] = acc;
  }
  __syncthreads();
  if (tid < 128){
    int tok = mem_tok[b*128 + tid];
    stk[tid] = tok;
    float sv = -1e9f;
    if (tok >= 0){
      const float* hr = H + ((size_t)b*T_ + tok)*D_;
      float a0=0,a1=0,a2=0,a3=0;
      for (int i=0;i<512;i+=4){
        a0 += hr[i]*qv[i]; a1 += hr[i+1]*qv[i+1];
        a2 += hr[i+2]*qv[i+2]; a3 += hr[i+3]*qv[i+3];
      }
      sv = (a0+a1)+(a2+a3);
    }
    sc[tid] = sv;
  }
  __syncthreads();
  if (tid < 64){
    float m = fmaxf(sc[tid], sc[tid+64]);
    #pragma unroll
    for (int off=32;off;off>>=1) m = fmaxf(m, __shfl_xor(m, off));
    if (tid == 0) red[0] = m;
  }
  __syncthreads();
  if (tid < 128) at[tid] = expf(sc[tid] - red[0]);
  __syncthreads();
  if (tid < 64){
    float s2 = at[tid] + at[tid+64];
    #pragma unroll
    for (int off=32;off;off>>=1) s2 += __shfl_xor(s2, off);
    if (tid == 0) red[1] = s2;
  }
  __syncthreads();
  if (tid < 128) at[tid] = at[tid] / red[1];
  __syncthreads();
  #pragma unroll
  for (int jj=0;jj<2;++jj){
    int d0 = tid + jj*256;
    float acc = 0.f;
    for (int n=0;n<128;++n){
      int tok = stk[n];
      if (tok < 0) continue;
      acc += at[n] * H[((size_t)b*T_ + tok)*D_ + d0];
    }
    ctxT[(size_t)d0*32 + b] = acc;   // [D][B] for uniform (scalar) loads downstream
  }
}

// ------- out projection: out[b][c] = sum_k ctxT[k][b]*out_w[k][c] + out_b[c]; f32 store -------
__global__ __launch_bounds__(256) void k_outproj(const float* __restrict__ ctxT,
    const float* __restrict__ outw, const float* __restrict__ outb, float* __restrict__ out){
  int c = blockIdx.x*256 + threadIdx.x;
  float acc[32];
  #pragma unroll
  for (int i=0;i<32;++i) acc[i] = 0.f;
  for (int k=0;k<512;++k){
    float wv = outw[(size_t)k*V_ + c];
    const float* ct = ctxT + k*32;     // uniform address -> scalar loads
    #pragma unroll
    for (int i=0;i<32;++i) acc[i] += ct[i]*wv;
  }
  float bo = outb[c];
  #pragma unroll
  for (int i=0;i<32;++i) out[(size_t)i*V_ + c] = acc[i] + bo;
}

extern "C" void kernel_launch(void* const* d_in, const int* in_sizes, int n_in,
                              void* d_out, int out_size, void* d_ws, size_t ws_size,
                              hipStream_t stream) {
  const int*   seq   = (const int*)  d_in[0];
  const float* embed = (const float*)d_in[1];
  const float* ff1w  = (const float*)d_in[2];
  const float* ff1b  = (const float*)d_in[3];
  const float* ff2w  = (const float*)d_in[4];
  const float* ff2b  = (const float*)d_in[5];
  const float* lng   = (const float*)d_in[6];
  const float* lnb   = (const float*)d_in[7];
  const float* wgw   = (const float*)d_in[8];
  const float* wgb   = (const float*)d_in[9];
  const float* demw  = (const float*)d_in[10];
  const float* demb  = (const float*)d_in[11];
  const float* qw    = (const float*)d_in[12];
  const float* qb    = (const float*)d_in[13];
  const float* outw  = (const float*)d_in[14];
  const float* outb  = (const float*)d_in[15];
  float* out = (float*)d_out;
  char* ws = (char*)d_ws;

  // workspace layout (bytes) — total ~50.4 MB
  float* H0     = (float*)(ws + 0);                      // 8192*512*4   = 16,777,216 (residual -> X in place)
  float* HID    = (float*)(ws + 16777216);               // 8192*1024*4  = 33,554,432 (hidden -> H after LN)
  float* Hbuf   = (float*)(ws + 16777216);               // aliases HID (dead after GEMM2)
  float* wsl    = (float*)(ws + 50331648);               // 8192*4
  float* dd     = (float*)(ws + 50364416);               // 8192*4
  int*   memtok = (int*)  (ws + 50397184);               // 32*128*4
  float* ctxT   = (float*)(ws + 50413568);               // 512*32*4

  k_gather<<<M_/2, 256, 0, stream>>>(seq, embed, H0);
  // HID = relu(H0 @ ff1_w + ff1_b)                  [8192 x 1024]
  k_gemm_f32<512, 1><<<128*16, 256, 0, stream>>>(H0, ff1w, ff1b, (const float*)nullptr, HID, 1024, 16);
  // H0 = HID @ ff2_w + ff2_b + H0   (in place)      [8192 x 512]
  k_gemm_f32<1024,2><<<128*8, 256, 0, stream>>>(HID, ff2w, ff2b, H0, H0, 512, 8);
  // Hbuf = LN(H0)  (HID region is dead now)
  k_ln      <<<M_/4, 256, 0, stream>>>(H0, lng, lnb, wgw, wgb, demw, demb, Hbuf, wsl, dd);
  k_scan    <<<B_, 64, 0, stream>>>(wsl, dd, memtok);
  k_readhead<<<B_, 256, 0, stream>>>(Hbuf, memtok, qw, qb, ctxT);
  k_outproj <<<V_/256, 256, 0, stream>>>(ctxT, outw, outb, out);
}